// Round 19
// baseline (5293.562 us; speedup 1.0000x reference)
//
#include <hip/hip_runtime.h>
#include <math.h>

#define EPSF 1e-5f

typedef _Float16 f16;
typedef __attribute__((ext_vector_type(8))) _Float16 f16x8;
typedef __attribute__((ext_vector_type(4))) float f32x4;

// ---------------- basis helpers ----------------
__device__ __forceinline__ void tap_geom(int tap, float hats[4], float xh[3], float& mask) {
  int d = tap / 25, h = (tap / 5) % 5, w = tap % 5;
  float X = (float)(d - 2), Y = (float)(h - 2), Z = (float)(w - 2);
  float r = sqrtf(X * X + Y * Y + Z * Z);
#pragma unroll
  for (int k = 0; k < 4; ++k) hats[k] = fmaxf(1.0f - fabsf(r - (float)k), 0.0f);
  float inv = (r > 0.0f) ? (1.0f / r) : 0.0f;
  xh[0] = X * inv; xh[1] = Y * inv; xh[2] = Z * inv;
  mask = (r > 0.0f) ? 1.0f : 0.0f;
}

// K1 (float4): [(i*125 + tap)*VEC + cv] -> {xh0*R, xh1*R, xh2*R, 0}
__global__ void build_k1(const float* __restrict__ w1, float* __restrict__ K1,
                         int VEC, int SIN) {
  int total = SIN * 125 * VEC;
  for (int idx = blockIdx.x * blockDim.x + threadIdx.x; idx < total;
       idx += gridDim.x * blockDim.x) {
    int cv = idx % VEC;
    int tap = (idx / VEC) % 125;
    int i = idx / (VEC * 125);
    float hats[4], xh[3], mask;
    tap_geom(tap, hats, xh, mask);
    float R = 0.f;
#pragma unroll
    for (int k = 0; k < 4; ++k) R += w1[(cv * SIN + i) * 4 + k] * hats[k];
    float* o = K1 + (long)idx * 4;
    o[0] = xh[0] * R; o[1] = xh[1] * R; o[2] = xh[2] * R; o[3] = 0.f;
  }
}

// ---- MFMA K2, COALESCED layout: K2L[((tap*KS + ks)*64 + lane)*8 + e] ----
__global__ void build_k2c(const float* __restrict__ wA, const float* __restrict__ wB,
                          f16* __restrict__ K2, int VEC, int SOUT, int KS) {
  int total = 125 * KS * 64 * 8;
  for (int idx = blockIdx.x * blockDim.x + threadIdx.x; idx < total;
       idx += gridDim.x * blockDim.x) {
    int e = idx & 7;
    int lane = (idx >> 3) & 63;
    int ks = (idx >> 9) % KS;
    int tap = idx / (KS << 9);
    int n = lane & 15;
    int g = lane >> 4;
    int c = (ks * 4 + g) * 8 + e;
    float val = 0.f;
    if (n < SOUT && c < VEC * 12) {
      float hats[4], xh[3], mask;
      tap_geom(tap, hats, xh, mask);
      int cv = c / 12, comp = c % 12;
      if (comp < 3) {
        float RA = 0.f;
#pragma unroll
        for (int k = 0; k < 4; ++k) RA += wA[(n * VEC + cv) * 4 + k] * hats[k];
        val = RA * xh[comp];
      } else {
        int ij = comp - 3;
        int ii = ij / 3, jj = ij % 3;
        float RB[3];
#pragma unroll
        for (int m = 0; m < 3; ++m) {
          float r = 0.f;
#pragma unroll
          for (int k = 0; k < 4; ++k) r += wB[((n * VEC + cv) * 3 + m) * 4 + k] * hats[k];
          RB[m] = r;
        }
        float a0 = (ii == jj) ? 1.0f : 0.0f;
        float a1 = 0.0f;
        if (ii != jj) {
          int l = 3 - ii - jj;
          float sgn = (((jj - ii + 3) % 3) == 1) ? 1.0f : -1.0f;
          a1 = sgn * xh[l];
        }
        float a2 = xh[ii] * xh[jj] - ((ii == jj) ? (mask / 3.0f) : 0.0f);
        val = RB[0] * a0 + RB[1] * a1 + RB[2] * a2;
      }
    }
    K2[idx] = (f16)val;
  }
}

// ------- conv1 single-pass v2: branch-free guards (speculatable loads) -------
// Clamped indices + select-to-zero make every load in-bounds, so the unrolled
// h-window lets the scheduler hoist next-row loads under current FMAs.
// fmaf(0,k,acc)==acc -> per-thread arithmetic identical to guarded version.
template <int SIN, int VEC, int CP8, int XT>
__global__ __launch_bounds__(64) void conv1_vt_x(const float* __restrict__ s,
                                                 const f32x4* __restrict__ K1,
                                                 f16* __restrict__ VT,
                                                 int Bc, int IS, int OS, int XG) {
  constexpr int NP = (VEC + 1) / 2;
  constexpr int NM = 2 * XT + 3;
  int iss = IS * IS * IS;
  long total = (long)Bc * OS * OS * XG * NP;
  for (long idx = blockIdx.x * (long)blockDim.x + threadIdx.x; idx < total;
       idx += gridDim.x * (long)blockDim.x) {
    int xg = (int)(idx % XG);
    int pp = (int)((idx / XG) % NP);
    int y  = (int)((idx / ((long)XG * NP)) % OS);
    int z  = (int)((idx / ((long)XG * NP * OS)) % OS);
    int b  = (int)(idx / ((long)XG * NP * OS * OS));
    int x0 = xg * XT;
    int cv0 = 2 * pp;
    int cv1 = (2 * pp + 1 < VEC) ? (2 * pp + 1) : (VEC - 1);

    // branch-free boundary precompute
    int zc[5], yc[5], xc[NM];
    bool zv[5], yv[5], xv[NM];
#pragma unroll
    for (int d = 0; d < 5; ++d) {
      int iz = 2 * z - 3 + d; zv[d] = (unsigned)iz < (unsigned)IS; zc[d] = zv[d] ? iz : 0;
      int iy = 2 * y - 3 + d; yv[d] = (unsigned)iy < (unsigned)IS; yc[d] = yv[d] ? iy : 0;
    }
#pragma unroll
    for (int m = 0; m < NM; ++m) {
      int xi = 2 * x0 - 3 + m; xv[m] = (unsigned)xi < (unsigned)IS; xc[m] = xv[m] ? xi : 0;
    }

    float acc[2][3][XT];
#pragma unroll
    for (int p = 0; p < 2; ++p)
#pragma unroll
      for (int c = 0; c < 3; ++c)
#pragma unroll
        for (int t = 0; t < XT; ++t) acc[p][c][t] = 0.f;

    const float* sb = s + (long)b * SIN * iss;
    const f32x4* kb = K1;
    for (int i = 0; i < SIN; ++i) {
      for (int d = 0; d < 5; ++d) {
        const float* sz = sb + zc[d] * IS * IS;
        bool vz = zv[d];
#pragma unroll
        for (int h = 0; h < 5; ++h) {
          const float* srow = sz + yc[h] * IS;
          bool vzh = vz && yv[h];
          float sv[NM];
#pragma unroll
          for (int m = 0; m < NM; ++m) {
            float v = srow[xc[m]];
            sv[m] = (vzh && xv[m]) ? v : 0.f;
          }
          const f32x4* krow = kb + (d * 25 + h * 5) * VEC;
#pragma unroll
          for (int w = 0; w < 5; ++w) {
            f32x4 k0 = krow[w * VEC + cv0];
            f32x4 k1 = krow[w * VEC + cv1];
#pragma unroll
            for (int t = 0; t < XT; ++t) {
              float sx = sv[2 * t + w];
              acc[0][0][t] = fmaf(sx, k0[0], acc[0][0][t]);
              acc[0][1][t] = fmaf(sx, k0[1], acc[0][1][t]);
              acc[0][2][t] = fmaf(sx, k0[2], acc[0][2][t]);
              acc[1][0][t] = fmaf(sx, k1[0], acc[1][0][t]);
              acc[1][1][t] = fmaf(sx, k1[1], acc[1][1][t]);
              acc[1][2][t] = fmaf(sx, k1[2], acc[1][2][t]);
            }
          }
        }
      }
      sb += iss;
      kb += 125 * VEC;
    }

    long ybase = (((long)(b * OS + z) * OS + y) * CP8) * (long)OS * 8;
    int cg0 = pp * 3;
#pragma unroll
    for (int t = 0; t < XT; ++t) {
      int x = x0 + t;
      if (x >= OS) continue;
      float a00 = acc[0][0][t], a01 = acc[0][1][t], a02 = acc[0][2][t];
      float a10 = acc[1][0][t], a11 = acc[1][1][t], a12 = acc[1][2][t];
      float v0[12] = {a00, a01, a02,
                      a00 * a00, a00 * a01, a00 * a02,
                      a01 * a00, a01 * a01, a01 * a02,
                      a02 * a00, a02 * a01, a02 * a02};
      float v1[12] = {a10, a11, a12,
                      a10 * a10, a10 * a11, a10 * a12,
                      a11 * a10, a11 * a11, a11 * a12,
                      a12 * a10, a12 * a11, a12 * a12};
      f16x8 pk0, pk1, pk2;
#pragma unroll
      for (int e = 0; e < 8; ++e) pk0[e] = (f16)v0[e];
#pragma unroll
      for (int e = 0; e < 4; ++e) { pk1[e] = (f16)v0[8 + e]; pk1[4 + e] = (f16)v1[e]; }
#pragma unroll
      for (int e = 0; e < 8; ++e) pk2[e] = (f16)v1[4 + e];
      long rowbase = ybase + (long)x * 8;
      *(f16x8*)(VT + rowbase + (long)(cg0 + 0) * OS * 8) = pk0;
      *(f16x8*)(VT + rowbase + (long)(cg0 + 1) * OS * 8) = pk1;
      *(f16x8*)(VT + rowbase + (long)(cg0 + 2) * OS * 8) = pk2;
    }
  }
}

// ------- conv1 pass A (SIN-split, blocks 3-4): partial v-triples per slice -------
template <int SIN, int NSL, int VEC>
__global__ __launch_bounds__(256) void conv1_part(const float* __restrict__ s,
                                                  const f32x4* __restrict__ K1,
                                                  float* __restrict__ Vp,
                                                  int Bc, int IS, int OS, int XG, int XP) {
  constexpr int NP = (VEC + 1) / 2;
  constexpr int SLC = SIN / NSL;
  constexpr int V3 = VEC * 3;
  int iss = IS * IS * IS;
  long total = (long)Bc * OS * OS * NP * NSL * XG;
  for (long idx = blockIdx.x * (long)blockDim.x + threadIdx.x; idx < total;
       idx += gridDim.x * (long)blockDim.x) {
    int xg = (int)(idx % XG);
    int sl = (int)((idx / XG) % NSL);
    int pp = (int)((idx / ((long)XG * NSL)) % NP);
    int y  = (int)((idx / ((long)XG * NSL * NP)) % OS);
    int z  = (int)((idx / ((long)XG * NSL * NP * OS)) % OS);
    int b  = (int)(idx / ((long)XG * NSL * NP * OS * OS));
    int x0 = xg * 4;
    int cv0 = 2 * pp;
    int cv1 = (2 * pp + 1 < VEC) ? (2 * pp + 1) : (VEC - 1);

    float acc[2][3][4];
#pragma unroll
    for (int p = 0; p < 2; ++p)
#pragma unroll
      for (int c = 0; c < 3; ++c)
#pragma unroll
        for (int t = 0; t < 4; ++t) acc[p][c][t] = 0.f;

    const float* sb = s + ((long)b * SIN + sl * SLC) * iss;
    const f32x4* kb = K1 + (long)(sl * SLC) * 125 * VEC;
    for (int i = 0; i < SLC; ++i) {
      for (int d = 0; d < 5; ++d) {
        int iz = 2 * z - 3 + d;
        if ((unsigned)iz >= (unsigned)IS) continue;
        for (int h = 0; h < 5; ++h) {
          int iy = 2 * y - 3 + h;
          if ((unsigned)iy >= (unsigned)IS) continue;
          const float* srow = sb + (iz * IS + iy) * IS;
          float sv[11];
#pragma unroll
          for (int m = 0; m < 11; ++m) {
            int xi = 2 * x0 - 3 + m;
            bool ok = (unsigned)xi < (unsigned)IS;
            sv[m] = ok ? srow[ok ? xi : 0] : 0.f;
          }
          const f32x4* krow = kb + (d * 25 + h * 5) * VEC;
#pragma unroll
          for (int w = 0; w < 5; ++w) {
            f32x4 k0 = krow[w * VEC + cv0];
            f32x4 k1 = krow[w * VEC + cv1];
#pragma unroll
            for (int t = 0; t < 4; ++t) {
              float sx = sv[2 * t + w];
              acc[0][0][t] = fmaf(sx, k0[0], acc[0][0][t]);
              acc[0][1][t] = fmaf(sx, k0[1], acc[0][1][t]);
              acc[0][2][t] = fmaf(sx, k0[2], acc[0][2][t]);
              acc[1][0][t] = fmaf(sx, k1[0], acc[1][0][t]);
              acc[1][1][t] = fmaf(sx, k1[1], acc[1][1][t]);
              acc[1][2][t] = fmaf(sx, k1[2], acc[1][2][t]);
            }
          }
        }
      }
      sb += iss;
      kb += 125 * VEC;
    }

    long row = (((long)sl * Bc + b) * OS + z) * OS + y;
    float* base = Vp + row * V3 * XP + x0;
#pragma unroll
    for (int p = 0; p < 2; ++p) {
      int cv = p ? cv1 : cv0;
#pragma unroll
      for (int c = 0; c < 3; ++c) {
        f32x4 st = {acc[p][c][0], acc[p][c][1], acc[p][c][2], acc[p][c][3]};
        *(f32x4*)(base + (long)(cv * 3 + c) * XP) = st;
      }
    }
  }
}

// ------- conv1 pass B: sum slices, t-products, pack VT -------
template <int VEC, int NSL, int CP8>
__global__ __launch_bounds__(256) void vt_pack(const float* __restrict__ Vp,
                                               f16* __restrict__ VT,
                                               int Bc, int OS, int XP) {
  constexpr int NP = (VEC + 1) / 2;
  constexpr int V3 = VEC * 3;
  long total = (long)Bc * OS * OS * NP * OS;
  for (long idx = blockIdx.x * (long)blockDim.x + threadIdx.x; idx < total;
       idx += gridDim.x * (long)blockDim.x) {
    int x  = (int)(idx % OS);
    int pp = (int)((idx / OS) % NP);
    int y  = (int)((idx / ((long)OS * NP)) % OS);
    int z  = (int)((idx / ((long)OS * NP * OS)) % OS);
    int b  = (int)(idx / ((long)OS * NP * OS * OS));
    int cv0 = 2 * pp;
    int cv1 = (2 * pp + 1 < VEC) ? (2 * pp + 1) : (VEC - 1);

    float a[6] = {0.f, 0.f, 0.f, 0.f, 0.f, 0.f};
    for (int sl = 0; sl < NSL; ++sl) {
      long row = (((long)sl * Bc + b) * OS + z) * OS + y;
      const float* base = Vp + row * V3 * XP + x;
#pragma unroll
      for (int c = 0; c < 3; ++c) {
        a[c]     += base[(long)(cv0 * 3 + c) * XP];
        a[3 + c] += base[(long)(cv1 * 3 + c) * XP];
      }
    }
    float a00 = a[0], a01 = a[1], a02 = a[2];
    float a10 = a[3], a11 = a[4], a12 = a[5];
    float v0[12] = {a00, a01, a02,
                    a00 * a00, a00 * a01, a00 * a02,
                    a01 * a00, a01 * a01, a01 * a02,
                    a02 * a00, a02 * a01, a02 * a02};
    float v1[12] = {a10, a11, a12,
                    a10 * a10, a10 * a11, a10 * a12,
                    a11 * a10, a11 * a11, a11 * a12,
                    a12 * a10, a12 * a11, a12 * a12};
    f16x8 pk0, pk1, pk2;
#pragma unroll
    for (int e = 0; e < 8; ++e) pk0[e] = (f16)v0[e];
#pragma unroll
    for (int e = 0; e < 4; ++e) { pk1[e] = (f16)v0[8 + e]; pk1[4 + e] = (f16)v1[e]; }
#pragma unroll
    for (int e = 0; e < 8; ++e) pk2[e] = (f16)v1[4 + e];
    long rowbase = (((long)(b * OS + z) * OS + y) * CP8) * (long)OS * 8 + (long)x * 8;
    int cg0 = pp * 3;
    *(f16x8*)(VT + rowbase + (long)(cg0 + 0) * OS * 8) = pk0;
    *(f16x8*)(VT + rowbase + (long)(cg0 + 1) * OS * 8) = pk1;
    *(f16x8*)(VT + rowbase + (long)(cg0 + 2) * OS * 8) = pk2;
  }
}

// ---------------- MFMA conv2: z-tiled wave + XCD swizzle + coalesced bf ----------------
template <int CP8, int SOUT, int ZT>
__global__ __launch_bounds__(256) void conv2_mfma(const f16* __restrict__ VT,
                                                  const f16* __restrict__ K2,
                                                  float* __restrict__ out,
                                                  int Bc, int IS, int OS, int XG, int ZG) {
  constexpr int KS = CP8 / 4;
  constexpr int NU = ZT + 4;
  int nwg = gridDim.x;
  int orig = blockIdx.x;
  int q = nwg >> 3, r = nwg & 7;
  int xcd = orig & 7, sub = orig >> 3;
  int swz = (xcd < r ? xcd * (q + 1) : r * (q + 1) + (xcd - r) * q) + sub;
  int wid = swz * (blockDim.x >> 6) + ((int)threadIdx.x >> 6);
  int lane = threadIdx.x & 63;
  int total = Bc * ZG * OS * XG;
  if (wid >= total) return;
  int xg = wid % XG;
  int y  = (wid / XG) % OS;
  int zg = (wid / (XG * OS)) % ZG;
  int b  = wid / (XG * OS * ZG);
  int z0 = zg * ZT;
  int x0 = xg * 16;
  int lm = lane & 15;
  int g  = lane >> 4;

  f32x4 acc[ZT];
#pragma unroll
  for (int t = 0; t < ZT; ++t) acc[t] = (f32x4){0.f, 0.f, 0.f, 0.f};

  const f16* kl = K2 + ((long)lane << 3);

  for (int h = 0; h < 5; ++h) {
    int yi = y - 3 + h;
    if ((unsigned)yi >= (unsigned)IS) continue;
    const f16* base[NU];
    bool zok[NU];
#pragma unroll
    for (int u = 0; u < NU; ++u) {
      int zi = z0 - 3 + u;
      zok[u] = (unsigned)zi < (unsigned)IS;
      int zc = zok[u] ? zi : 0;
      base[u] = VT + (((long)(b * IS + zc) * IS + yi) * CP8) * (long)IS * 8;
    }
    int hw = h * 5;
#pragma unroll 1
    for (int w = 0; w < 5; ++w) {
      int xi = x0 + lm - 3 + w;
      bool xok = (unsigned)xi < (unsigned)IS;
#pragma unroll
      for (int ks = 0; ks < KS; ++ks) {
        f16x8 bf[5];
#pragma unroll
        for (int d = 0; d < 5; ++d)
          bf[d] = *(const f16x8*)(kl + ((long)((d * 25 + hw + w) * KS + ks) << 9));
        f16x8 af[NU];
#pragma unroll
        for (int u = 0; u < NU; ++u) {
          af[u] = (f16x8){};
          if (zok[u] && xok)
            af[u] = *(const f16x8*)(base[u] + ((ks * 4 + g) * IS + xi) * 8);
        }
#pragma unroll
        for (int u = 0; u < NU; ++u) {
#pragma unroll
          for (int t = 0; t < ZT; ++t) {
            int d = u - t;
            if (d >= 0 && d <= 4)
              acc[t] = __builtin_amdgcn_mfma_f32_16x16x32_f16(af[u], bf[d], acc[t], 0, 0, 0);
          }
        }
      }
    }
  }
  if (lm < SOUT) {
    int oss = OS * OS * OS;
#pragma unroll
    for (int t = 0; t < ZT; ++t) {
      int z = z0 + t;
      if (z < OS) {
        float* op = out + ((long)b * SOUT + lm) * oss + (z * OS + y) * OS;
#pragma unroll
        for (int r2 = 0; r2 < 4; ++r2) {
          int xm = x0 + g * 4 + r2;
          if (xm < OS) op[xm] = acc[t][r2];
        }
      }
    }
  }
}

// ---------------- batch-norm reductions (two-stage, deterministic) ----------------
__global__ void stats1(const float* __restrict__ a, float* __restrict__ part,
                       int B, int C, int ss, int nblk) {
  int c = blockIdx.y;
  int tid = threadIdx.x;
  float s = 0.f, s2 = 0.f;
  for (int b = 0; b < B; ++b) {
    const float* ab = a + ((long)b * C + c) * ss;
    for (int p = blockIdx.x * blockDim.x + tid; p < ss; p += nblk * blockDim.x) {
      float x = ab[p];
      s += x;
      s2 += x * x;
    }
  }
  __shared__ float sh[256], sh2[256];
  sh[tid] = s; sh2[tid] = s2;
  __syncthreads();
  for (int off = 128; off > 0; off >>= 1) {
    if (tid < off) { sh[tid] += sh[tid + off]; sh2[tid] += sh2[tid + off]; }
    __syncthreads();
  }
  if (tid == 0) {
    part[(c * nblk + blockIdx.x) * 2 + 0] = sh[0];
    part[(c * nblk + blockIdx.x) * 2 + 1] = sh2[0];
  }
}

__global__ void stats2(const float* __restrict__ part, float* __restrict__ stats,
                       int nblk, float invn) {
  int c = blockIdx.x;
  int tid = threadIdx.x;
  float s = 0.f, s2 = 0.f;
  for (int i = tid; i < nblk; i += blockDim.x) {
    s += part[(c * nblk + i) * 2 + 0];
    s2 += part[(c * nblk + i) * 2 + 1];
  }
  __shared__ float sh[256], sh2[256];
  sh[tid] = s; sh2[tid] = s2;
  __syncthreads();
  for (int off = 128; off > 0; off >>= 1) {
    if (tid < off) { sh[tid] += sh[tid + off]; sh2[tid] += sh2[tid + off]; }
    __syncthreads();
  }
  if (tid == 0) {
    float m = sh[0] * invn;
    float var = sh2[0] * invn - m * m;
    stats[c * 2 + 0] = m;
    stats[c * 2 + 1] = 1.0f / sqrtf(var + EPSF);
  }
}

__global__ void bn_apply(const float* __restrict__ in, float* __restrict__ out,
                         const float* __restrict__ stats, const float* __restrict__ g,
                         const float* __restrict__ be, const float* __restrict__ bias,
                         int C, int ss, int relu) {
  int bc = blockIdx.y;
  int c = bc % C;
  float m = stats[c * 2 + 0];
  float r = stats[c * 2 + 1];
  float ga = g ? g[c] : 1.f;
  float bb = be ? be[c] : 0.f;
  float bi = bias ? bias[c] : 0.f;
  const float* ip = in + (long)bc * ss;
  float* op = out + (long)bc * ss;
  for (int p = blockIdx.x * blockDim.x + threadIdx.x; p < ss; p += gridDim.x * blockDim.x) {
    float xn = (ip[p] - m) * r * ga + bb;
    if (relu) xn = fmaxf(xn + bi, 0.f);
    op[p] = xn;
  }
}

// ---------------- pooling + final batch-norm ----------------
__global__ void pool_k(const float* __restrict__ in, float* __restrict__ pooled, int ss) {
  int bc = blockIdx.x;
  int tid = threadIdx.x;
  const float* p = in + (long)bc * ss;
  float s = 0.f;
  for (int e = tid; e < ss; e += blockDim.x) s += p[e];
  __shared__ float sh[256];
  sh[tid] = s;
  __syncthreads();
  for (int off = 128; off > 0; off >>= 1) {
    if (tid < off) sh[tid] += sh[tid + off];
    __syncthreads();
  }
  if (tid == 0) pooled[bc] = sh[0] / (float)ss;
}

__global__ void final_bn(const float* __restrict__ pooled, const float* __restrict__ g,
                         const float* __restrict__ be, float* __restrict__ out,
                         int B, int C) {
  int tid = threadIdx.x;
  __shared__ float mv[16][2];
  if (tid < C) {
    float s = 0.f, s2 = 0.f;
    for (int b = 0; b < B; ++b) {
      float x = pooled[b * C + tid];
      s += x;
      s2 += x * x;
    }
    float m = s / (float)B;
    float var = s2 / (float)B - m * m;
    mv[tid][0] = m;
    mv[tid][1] = 1.0f / sqrtf(var + EPSF);
  }
  __syncthreads();
  for (int i = tid; i < B * C; i += blockDim.x) {
    int c = i % C;
    out[i] = g[c] * (pooled[i] - mv[c][0]) * mv[c][1] + be[c];
  }
}

// ---------------- host ----------------
extern "C" void kernel_launch(void* const* d_in, const int* in_sizes, int n_in,
                              void* d_out, int out_size, void* d_ws, size_t ws_size,
                              hipStream_t stream) {
  (void)in_sizes; (void)n_in; (void)out_size; (void)ws_size;
  const float* x = (const float*)d_in[0];
  const float* w1[5]; const float* wA[5]; const float* wB[5];
  const float* bias[5]; const float* gam[5]; const float* bet[5];
  for (int i = 0; i < 5; ++i) {
    w1[i]  = (const float*)d_in[1 + i * 6 + 0];
    wA[i]  = (const float*)d_in[1 + i * 6 + 1];
    wB[i]  = (const float*)d_in[1 + i * 6 + 2];
    bias[i]= (const float*)d_in[1 + i * 6 + 3];
    gam[i] = (const float*)d_in[1 + i * 6 + 4];
    bet[i] = (const float*)d_in[1 + i * 6 + 5];
  }
  const float* gamma_out = (const float*)d_in[31];
  const float* beta_out  = (const float*)d_in[32];
  float* out = (float*)d_out;

  // workspace carve (~135 MB)
  float* A     = (float*)d_ws;            // 8,388,608
  float* Bb    = A + 8388608;             // 10,976,000
  float* V     = Bb + 10976000;           // 13,799,808 floats (f16 VT = 27.6M f16)
  float* K1    = V + 13799808;            // 128,000 floats (float4 K1)
  float* K2    = K1 + 128000;             // 384,000 floats (f16 K2L)
  float* part  = K2 + 384000;             // 8,192
  float* stats = part + 16 * 256 * 2;
  float* pooled= stats + 64;
  f16* VT  = (f16*)V;
  f16* K2h = (f16*)K2;

  const int NB = 256;
  const int Bn = 32;

  // --- input batch-norm (C=1, no affine) ---
  {
    int ss = 64 * 64 * 64;
    stats1<<<dim3(NB, 1), 256, 0, stream>>>(x, part, Bn, 1, ss, NB);
    stats2<<<1, 256, 0, stream>>>(part, stats, NB, 1.0f / (float)(Bn * (long)ss));
    int gx = (ss + 255) / 256;
    bn_apply<<<dim3(gx, Bn), 256, 0, stream>>>(x, A, stats, nullptr, nullptr, nullptr, 1, ss, 0);
  }

  const int SINs[5]  = {1, 8, 16, 16, 16};
  const int SOUTs[5] = {8, 16, 16, 16, 10};
  const int VECs[5]  = {4, 12, 16, 16, 13};
  const int ISs[5]   = {64, 35, 21, 14, 10};
  const int VSs[5]   = {33, 19, 12, 8, 6};
  const int OSs[5]   = {35, 21, 14, 10, 8};
  const int CP8s[5]  = {8, 24, 24, 24, 24};
  const int CHKs[5]  = {8, 16, 32, 32, 32};
  const int NPs[5]   = {2, 6, 8, 8, 7};
  const int ZTs[5]   = {8, 8, 8, 4, 4};

  float* sbuf = A;
  for (int i = 0; i < 5; ++i) {
    float* obuf = (i % 2 == 0) ? Bb : A;
    int IS = ISs[i], VS = VSs[i], OS = OSs[i];
    int VEC = VECs[i], SIN = SINs[i], SOUT = SOUTs[i];

    { int t = SIN * 125 * VEC;
      build_k1<<<(t + 255) / 256, 256, 0, stream>>>(w1[i], K1, VEC, SIN); }

    int CP8 = CP8s[i];
    int KS = CP8 / 4;
    int CHK = CHKs[i];
    int XG = (OS + 15) / 16;
    int ZTi = ZTs[i];
    int ZG = (OS + ZTi - 1) / ZTi;
    { int t = 125 * KS * 512;
      build_k2c<<<(t + 255) / 256, 256, 0, stream>>>(wA[i], wB[i], K2h, VEC, SOUT, KS); }
    for (int b0 = 0; b0 < Bn; b0 += CHK) {
      int bc = CHK;
      const float* sp = sbuf + (long)b0 * SIN * IS * IS * IS;
      float* op = obuf + (long)b0 * SOUT * OS * OS * OS;
      long waves = (long)bc * ZG * OS * XG;
      int g2 = (int)((waves * 64 + 255) / 256);
      if (i == 0) {
        int XG1 = (VS + 3) / 4;
        long t1 = (long)bc * VS * VS * XG1 * NPs[i];
        int g1 = (int)((t1 + 63) / 64);
        conv1_vt_x<1, 4, 8, 4><<<g1, 64, 0, stream>>>(sp, (const f32x4*)K1, VT, bc, IS, VS, XG1);
        conv2_mfma<8, 8, 8><<<g2, 256, 0, stream>>>(VT, K2h, op, bc, VS, OS, XG, ZG);
      } else if (i == 1) {
        int XG1 = (VS + 3) / 4;
        long t1 = (long)bc * VS * VS * XG1 * NPs[i];
        int g1 = (int)((t1 + 63) / 64);
        conv1_vt_x<8, 12, 24, 4><<<g1, 64, 0, stream>>>(sp, (const f32x4*)K1, VT, bc, IS, VS, XG1);
        conv2_mfma<24, 16, 8><<<g2, 256, 0, stream>>>(VT, K2h, op, bc, VS, OS, XG, ZG);
      } else if (i == 2) {
        int XG1 = (VS + 3) / 4;
        long t1 = (long)bc * VS * VS * XG1 * NPs[i];
        int g1 = (int)((t1 + 63) / 64);
        conv1_vt_x<16, 16, 24, 4><<<g1, 64, 0, stream>>>(sp, (const f32x4*)K1, VT, bc, IS, VS, XG1);
        conv2_mfma<24, 16, 8><<<g2, 256, 0, stream>>>(VT, K2h, op, bc, VS, OS, XG, ZG);
      } else {
        int XG1 = (VS + 3) / 4;
        int XP1 = XG1 * 4;
        float* Vp = obuf;
        long tA = (long)bc * VS * VS * NPs[i] * 4 * XG1;
        int gA = (int)((tA + 255) / 256);
        long tB = (long)bc * VS * VS * NPs[i] * VS;
        int gB = (int)((tB + 255) / 256);
        if (i == 3) {
          conv1_part<16, 4, 16><<<gA, 256, 0, stream>>>(sp, (const f32x4*)K1, Vp, bc, IS, VS, XG1, XP1);
          vt_pack<16, 4, 24><<<gB, 256, 0, stream>>>(Vp, VT, bc, VS, XP1);
          conv2_mfma<24, 16, 4><<<g2, 256, 0, stream>>>(VT, K2h, op, bc, VS, OS, XG, ZG);
        } else {
          conv1_part<16, 4, 13><<<gA, 256, 0, stream>>>(sp, (const f32x4*)K1, Vp, bc, IS, VS, XG1, XP1);
          vt_pack<13, 4, 24><<<gB, 256, 0, stream>>>(Vp, VT, bc, VS, XP1);
          conv2_mfma<24, 10, 4><<<g2, 256, 0, stream>>>(VT, K2h, op, bc, VS, OS, XG, ZG);
        }
      }
    }

    { int ss = OS * OS * OS;
      stats1<<<dim3(NB, SOUT), 256, 0, stream>>>(obuf, part, Bn, SOUT, ss, NB);
      stats2<<<SOUT, 256, 0, stream>>>(part, stats, NB, 1.0f / (float)((long)Bn * ss));
      int gx = (ss + 255) / 256;
      bn_apply<<<dim3(gx, Bn * SOUT), 256, 0, stream>>>(obuf, obuf, stats, gam[i], bet[i],
                                                        bias[i], SOUT, ss, (i < 4) ? 1 : 0);
    }
    sbuf = obuf;
  }

  pool_k<<<Bn * 10, 256, 0, stream>>>(sbuf, pooled, 8 * 8 * 8);
  final_bn<<<1, 64, 0, stream>>>(pooled, gamma_out, beta_out, out, Bn, 10);
}

// Round 20
// 3153.154 us; speedup vs baseline: 1.6788x; 1.6788x over previous
//
#include <hip/hip_runtime.h>
#include <math.h>

#define EPSF 1e-5f

typedef _Float16 f16;
typedef __attribute__((ext_vector_type(8))) _Float16 f16x8;
typedef __attribute__((ext_vector_type(4))) float f32x4;

// ---------------- basis helpers ----------------
__device__ __forceinline__ void tap_geom(int tap, float hats[4], float xh[3], float& mask) {
  int d = tap / 25, h = (tap / 5) % 5, w = tap % 5;
  float X = (float)(d - 2), Y = (float)(h - 2), Z = (float)(w - 2);
  float r = sqrtf(X * X + Y * Y + Z * Z);
#pragma unroll
  for (int k = 0; k < 4; ++k) hats[k] = fmaxf(1.0f - fabsf(r - (float)k), 0.0f);
  float inv = (r > 0.0f) ? (1.0f / r) : 0.0f;
  xh[0] = X * inv; xh[1] = Y * inv; xh[2] = Z * inv;
  mask = (r > 0.0f) ? 1.0f : 0.0f;
}

// K1 (float4): [(i*125 + tap)*VEC + cv] -> {xh0*R, xh1*R, xh2*R, 0}
__global__ void build_k1(const float* __restrict__ w1, float* __restrict__ K1,
                         int VEC, int SIN) {
  int total = SIN * 125 * VEC;
  for (int idx = blockIdx.x * blockDim.x + threadIdx.x; idx < total;
       idx += gridDim.x * blockDim.x) {
    int cv = idx % VEC;
    int tap = (idx / VEC) % 125;
    int i = idx / (VEC * 125);
    float hats[4], xh[3], mask;
    tap_geom(tap, hats, xh, mask);
    float R = 0.f;
#pragma unroll
    for (int k = 0; k < 4; ++k) R += w1[(cv * SIN + i) * 4 + k] * hats[k];
    float* o = K1 + (long)idx * 4;
    o[0] = xh[0] * R; o[1] = xh[1] * R; o[2] = xh[2] * R; o[3] = 0.f;
  }
}

// ---- MFMA K2, COALESCED layout: K2L[((tap*KS + ks)*64 + lane)*8 + e] ----
__global__ void build_k2c(const float* __restrict__ wA, const float* __restrict__ wB,
                          f16* __restrict__ K2, int VEC, int SOUT, int KS) {
  int total = 125 * KS * 64 * 8;
  for (int idx = blockIdx.x * blockDim.x + threadIdx.x; idx < total;
       idx += gridDim.x * blockDim.x) {
    int e = idx & 7;
    int lane = (idx >> 3) & 63;
    int ks = (idx >> 9) % KS;
    int tap = idx / (KS << 9);
    int n = lane & 15;
    int g = lane >> 4;
    int c = (ks * 4 + g) * 8 + e;
    float val = 0.f;
    if (n < SOUT && c < VEC * 12) {
      float hats[4], xh[3], mask;
      tap_geom(tap, hats, xh, mask);
      int cv = c / 12, comp = c % 12;
      if (comp < 3) {
        float RA = 0.f;
#pragma unroll
        for (int k = 0; k < 4; ++k) RA += wA[(n * VEC + cv) * 4 + k] * hats[k];
        val = RA * xh[comp];
      } else {
        int ij = comp - 3;
        int ii = ij / 3, jj = ij % 3;
        float RB[3];
#pragma unroll
        for (int m = 0; m < 3; ++m) {
          float r = 0.f;
#pragma unroll
          for (int k = 0; k < 4; ++k) r += wB[((n * VEC + cv) * 3 + m) * 4 + k] * hats[k];
          RB[m] = r;
        }
        float a0 = (ii == jj) ? 1.0f : 0.0f;
        float a1 = 0.0f;
        if (ii != jj) {
          int l = 3 - ii - jj;
          float sgn = (((jj - ii + 3) % 3) == 1) ? 1.0f : -1.0f;
          a1 = sgn * xh[l];
        }
        float a2 = xh[ii] * xh[jj] - ((ii == jj) ? (mask / 3.0f) : 0.0f);
        val = RB[0] * a0 + RB[1] * a1 + RB[2] * a2;
      }
    }
    K2[idx] = (f16)val;
  }
}

// ------- conv1 single-pass: thread per (b,z,y,xg(XT),pp) -------
template <int SIN, int VEC, int CP8, int XT>
__global__ __launch_bounds__(256) void conv1_vt_x(const float* __restrict__ s,
                                                  const f32x4* __restrict__ K1,
                                                  f16* __restrict__ VT,
                                                  int Bc, int IS, int OS, int XG) {
  constexpr int NP = (VEC + 1) / 2;
  constexpr int NM = 2 * XT + 3;
  int iss = IS * IS * IS;
  long total = (long)Bc * OS * OS * XG * NP;
  for (long idx = blockIdx.x * (long)blockDim.x + threadIdx.x; idx < total;
       idx += gridDim.x * (long)blockDim.x) {
    int xg = (int)(idx % XG);
    int pp = (int)((idx / XG) % NP);
    int y  = (int)((idx / ((long)XG * NP)) % OS);
    int z  = (int)((idx / ((long)XG * NP * OS)) % OS);
    int b  = (int)(idx / ((long)XG * NP * OS * OS));
    int x0 = xg * XT;
    int cv0 = 2 * pp;
    int cv1 = (2 * pp + 1 < VEC) ? (2 * pp + 1) : (VEC - 1);

    float acc[2][3][XT];
#pragma unroll
    for (int p = 0; p < 2; ++p)
#pragma unroll
      for (int c = 0; c < 3; ++c)
#pragma unroll
        for (int t = 0; t < XT; ++t) acc[p][c][t] = 0.f;

    const float* sb = s + (long)b * SIN * iss;
    const f32x4* kb = K1;
    for (int i = 0; i < SIN; ++i) {
      for (int d = 0; d < 5; ++d) {
        int iz = 2 * z - 3 + d;
        if ((unsigned)iz >= (unsigned)IS) continue;
        for (int h = 0; h < 5; ++h) {
          int iy = 2 * y - 3 + h;
          if ((unsigned)iy >= (unsigned)IS) continue;
          const float* srow = sb + (iz * IS + iy) * IS;
          float sv[NM];
#pragma unroll
          for (int m = 0; m < NM; ++m) {
            int xi = 2 * x0 - 3 + m;
            bool ok = (unsigned)xi < (unsigned)IS;
            sv[m] = ok ? srow[ok ? xi : 0] : 0.f;
          }
          const f32x4* krow = kb + (d * 25 + h * 5) * VEC;
#pragma unroll
          for (int w = 0; w < 5; ++w) {
            f32x4 k0 = krow[w * VEC + cv0];
            f32x4 k1 = krow[w * VEC + cv1];
#pragma unroll
            for (int t = 0; t < XT; ++t) {
              float sx = sv[2 * t + w];
              acc[0][0][t] = fmaf(sx, k0[0], acc[0][0][t]);
              acc[0][1][t] = fmaf(sx, k0[1], acc[0][1][t]);
              acc[0][2][t] = fmaf(sx, k0[2], acc[0][2][t]);
              acc[1][0][t] = fmaf(sx, k1[0], acc[1][0][t]);
              acc[1][1][t] = fmaf(sx, k1[1], acc[1][1][t]);
              acc[1][2][t] = fmaf(sx, k1[2], acc[1][2][t]);
            }
          }
        }
      }
      sb += iss;
      kb += 125 * VEC;
    }

    long ybase = (((long)(b * OS + z) * OS + y) * CP8) * (long)OS * 8;
    int cg0 = pp * 3;
#pragma unroll
    for (int t = 0; t < XT; ++t) {
      int x = x0 + t;
      if (x >= OS) continue;
      float a00 = acc[0][0][t], a01 = acc[0][1][t], a02 = acc[0][2][t];
      float a10 = acc[1][0][t], a11 = acc[1][1][t], a12 = acc[1][2][t];
      float v0[12] = {a00, a01, a02,
                      a00 * a00, a00 * a01, a00 * a02,
                      a01 * a00, a01 * a01, a01 * a02,
                      a02 * a00, a02 * a01, a02 * a02};
      float v1[12] = {a10, a11, a12,
                      a10 * a10, a10 * a11, a10 * a12,
                      a11 * a10, a11 * a11, a11 * a12,
                      a12 * a10, a12 * a11, a12 * a12};
      f16x8 pk0, pk1, pk2;
#pragma unroll
      for (int e = 0; e < 8; ++e) pk0[e] = (f16)v0[e];
#pragma unroll
      for (int e = 0; e < 4; ++e) { pk1[e] = (f16)v0[8 + e]; pk1[4 + e] = (f16)v1[e]; }
#pragma unroll
      for (int e = 0; e < 8; ++e) pk2[e] = (f16)v1[4 + e];
      long rowbase = ybase + (long)x * 8;
      *(f16x8*)(VT + rowbase + (long)(cg0 + 0) * OS * 8) = pk0;
      *(f16x8*)(VT + rowbase + (long)(cg0 + 1) * OS * 8) = pk1;
      *(f16x8*)(VT + rowbase + (long)(cg0 + 2) * OS * 8) = pk2;
    }
  }
}

// ------- conv1 pass A (SIN-split, blocks 3-4): partial v-triples per slice -------
template <int SIN, int NSL, int VEC>
__global__ __launch_bounds__(256) void conv1_part(const float* __restrict__ s,
                                                  const f32x4* __restrict__ K1,
                                                  float* __restrict__ Vp,
                                                  int Bc, int IS, int OS, int XG, int XP) {
  constexpr int NP = (VEC + 1) / 2;
  constexpr int SLC = SIN / NSL;
  constexpr int V3 = VEC * 3;
  int iss = IS * IS * IS;
  long total = (long)Bc * OS * OS * NP * NSL * XG;
  for (long idx = blockIdx.x * (long)blockDim.x + threadIdx.x; idx < total;
       idx += gridDim.x * (long)blockDim.x) {
    int xg = (int)(idx % XG);
    int sl = (int)((idx / XG) % NSL);
    int pp = (int)((idx / ((long)XG * NSL)) % NP);
    int y  = (int)((idx / ((long)XG * NSL * NP)) % OS);
    int z  = (int)((idx / ((long)XG * NSL * NP * OS)) % OS);
    int b  = (int)(idx / ((long)XG * NSL * NP * OS * OS));
    int x0 = xg * 4;
    int cv0 = 2 * pp;
    int cv1 = (2 * pp + 1 < VEC) ? (2 * pp + 1) : (VEC - 1);

    float acc[2][3][4];
#pragma unroll
    for (int p = 0; p < 2; ++p)
#pragma unroll
      for (int c = 0; c < 3; ++c)
#pragma unroll
        for (int t = 0; t < 4; ++t) acc[p][c][t] = 0.f;

    const float* sb = s + ((long)b * SIN + sl * SLC) * iss;
    const f32x4* kb = K1 + (long)(sl * SLC) * 125 * VEC;
    for (int i = 0; i < SLC; ++i) {
      for (int d = 0; d < 5; ++d) {
        int iz = 2 * z - 3 + d;
        if ((unsigned)iz >= (unsigned)IS) continue;
        for (int h = 0; h < 5; ++h) {
          int iy = 2 * y - 3 + h;
          if ((unsigned)iy >= (unsigned)IS) continue;
          const float* srow = sb + (iz * IS + iy) * IS;
          float sv[11];
#pragma unroll
          for (int m = 0; m < 11; ++m) {
            int xi = 2 * x0 - 3 + m;
            bool ok = (unsigned)xi < (unsigned)IS;
            sv[m] = ok ? srow[ok ? xi : 0] : 0.f;
          }
          const f32x4* krow = kb + (d * 25 + h * 5) * VEC;
#pragma unroll
          for (int w = 0; w < 5; ++w) {
            f32x4 k0 = krow[w * VEC + cv0];
            f32x4 k1 = krow[w * VEC + cv1];
#pragma unroll
            for (int t = 0; t < 4; ++t) {
              float sx = sv[2 * t + w];
              acc[0][0][t] = fmaf(sx, k0[0], acc[0][0][t]);
              acc[0][1][t] = fmaf(sx, k0[1], acc[0][1][t]);
              acc[0][2][t] = fmaf(sx, k0[2], acc[0][2][t]);
              acc[1][0][t] = fmaf(sx, k1[0], acc[1][0][t]);
              acc[1][1][t] = fmaf(sx, k1[1], acc[1][1][t]);
              acc[1][2][t] = fmaf(sx, k1[2], acc[1][2][t]);
            }
          }
        }
      }
      sb += iss;
      kb += 125 * VEC;
    }

    long row = (((long)sl * Bc + b) * OS + z) * OS + y;
    float* base = Vp + row * V3 * XP + x0;
#pragma unroll
    for (int p = 0; p < 2; ++p) {
      int cv = p ? cv1 : cv0;
#pragma unroll
      for (int c = 0; c < 3; ++c) {
        f32x4 st = {acc[p][c][0], acc[p][c][1], acc[p][c][2], acc[p][c][3]};
        *(f32x4*)(base + (long)(cv * 3 + c) * XP) = st;
      }
    }
  }
}

// ------- conv1 pass B: sum slices, t-products, pack VT -------
template <int VEC, int NSL, int CP8>
__global__ __launch_bounds__(256) void vt_pack(const float* __restrict__ Vp,
                                               f16* __restrict__ VT,
                                               int Bc, int OS, int XP) {
  constexpr int NP = (VEC + 1) / 2;
  constexpr int V3 = VEC * 3;
  long total = (long)Bc * OS * OS * NP * OS;
  for (long idx = blockIdx.x * (long)blockDim.x + threadIdx.x; idx < total;
       idx += gridDim.x * (long)blockDim.x) {
    int x  = (int)(idx % OS);
    int pp = (int)((idx / OS) % NP);
    int y  = (int)((idx / ((long)OS * NP)) % OS);
    int z  = (int)((idx / ((long)OS * NP * OS)) % OS);
    int b  = (int)(idx / ((long)OS * NP * OS * OS));
    int cv0 = 2 * pp;
    int cv1 = (2 * pp + 1 < VEC) ? (2 * pp + 1) : (VEC - 1);

    float a[6] = {0.f, 0.f, 0.f, 0.f, 0.f, 0.f};
    for (int sl = 0; sl < NSL; ++sl) {
      long row = (((long)sl * Bc + b) * OS + z) * OS + y;
      const float* base = Vp + row * V3 * XP + x;
#pragma unroll
      for (int c = 0; c < 3; ++c) {
        a[c]     += base[(long)(cv0 * 3 + c) * XP];
        a[3 + c] += base[(long)(cv1 * 3 + c) * XP];
      }
    }
    float a00 = a[0], a01 = a[1], a02 = a[2];
    float a10 = a[3], a11 = a[4], a12 = a[5];
    float v0[12] = {a00, a01, a02,
                    a00 * a00, a00 * a01, a00 * a02,
                    a01 * a00, a01 * a01, a01 * a02,
                    a02 * a00, a02 * a01, a02 * a02};
    float v1[12] = {a10, a11, a12,
                    a10 * a10, a10 * a11, a10 * a12,
                    a11 * a10, a11 * a11, a11 * a12,
                    a12 * a10, a12 * a11, a12 * a12};
    f16x8 pk0, pk1, pk2;
#pragma unroll
    for (int e = 0; e < 8; ++e) pk0[e] = (f16)v0[e];
#pragma unroll
    for (int e = 0; e < 4; ++e) { pk1[e] = (f16)v0[8 + e]; pk1[4 + e] = (f16)v1[e]; }
#pragma unroll
    for (int e = 0; e < 8; ++e) pk2[e] = (f16)v1[4 + e];
    long rowbase = (((long)(b * OS + z) * OS + y) * CP8) * (long)OS * 8 + (long)x * 8;
    int cg0 = pp * 3;
    *(f16x8*)(VT + rowbase + (long)(cg0 + 0) * OS * 8) = pk0;
    *(f16x8*)(VT + rowbase + (long)(cg0 + 1) * OS * 8) = pk1;
    *(f16x8*)(VT + rowbase + (long)(cg0 + 2) * OS * 8) = pk2;
  }
}

// ---------------- MFMA conv2: z-tiled wave + XCD swizzle + coalesced bf ----------------
template <int CP8, int SOUT, int ZT>
__global__ __launch_bounds__(256) void conv2_mfma(const f16* __restrict__ VT,
                                                  const f16* __restrict__ K2,
                                                  float* __restrict__ out,
                                                  int Bc, int IS, int OS, int XG, int ZG) {
  constexpr int KS = CP8 / 4;
  constexpr int NU = ZT + 4;
  int nwg = gridDim.x;
  int orig = blockIdx.x;
  int q = nwg >> 3, r = nwg & 7;
  int xcd = orig & 7, sub = orig >> 3;
  int swz = (xcd < r ? xcd * (q + 1) : r * (q + 1) + (xcd - r) * q) + sub;
  int wid = swz * (blockDim.x >> 6) + ((int)threadIdx.x >> 6);
  int lane = threadIdx.x & 63;
  int total = Bc * ZG * OS * XG;
  if (wid >= total) return;
  int xg = wid % XG;
  int y  = (wid / XG) % OS;
  int zg = (wid / (XG * OS)) % ZG;
  int b  = wid / (XG * OS * ZG);
  int z0 = zg * ZT;
  int x0 = xg * 16;
  int lm = lane & 15;
  int g  = lane >> 4;

  f32x4 acc[ZT];
#pragma unroll
  for (int t = 0; t < ZT; ++t) acc[t] = (f32x4){0.f, 0.f, 0.f, 0.f};

  const f16* kl = K2 + ((long)lane << 3);

  for (int h = 0; h < 5; ++h) {
    int yi = y - 3 + h;
    if ((unsigned)yi >= (unsigned)IS) continue;
    const f16* base[NU];
    bool zok[NU];
#pragma unroll
    for (int u = 0; u < NU; ++u) {
      int zi = z0 - 3 + u;
      zok[u] = (unsigned)zi < (unsigned)IS;
      int zc = zok[u] ? zi : 0;
      base[u] = VT + (((long)(b * IS + zc) * IS + yi) * CP8) * (long)IS * 8;
    }
    int hw = h * 5;
#pragma unroll 1
    for (int w = 0; w < 5; ++w) {
      int xi = x0 + lm - 3 + w;
      bool xok = (unsigned)xi < (unsigned)IS;
#pragma unroll
      for (int ks = 0; ks < KS; ++ks) {
        f16x8 bf[5];
#pragma unroll
        for (int d = 0; d < 5; ++d)
          bf[d] = *(const f16x8*)(kl + ((long)((d * 25 + hw + w) * KS + ks) << 9));
        f16x8 af[NU];
#pragma unroll
        for (int u = 0; u < NU; ++u) {
          af[u] = (f16x8){};
          if (zok[u] && xok)
            af[u] = *(const f16x8*)(base[u] + ((ks * 4 + g) * IS + xi) * 8);
        }
#pragma unroll
        for (int u = 0; u < NU; ++u) {
#pragma unroll
          for (int t = 0; t < ZT; ++t) {
            int d = u - t;
            if (d >= 0 && d <= 4)
              acc[t] = __builtin_amdgcn_mfma_f32_16x16x32_f16(af[u], bf[d], acc[t], 0, 0, 0);
          }
        }
      }
    }
  }
  if (lm < SOUT) {
    int oss = OS * OS * OS;
#pragma unroll
    for (int t = 0; t < ZT; ++t) {
      int z = z0 + t;
      if (z < OS) {
        float* op = out + ((long)b * SOUT + lm) * oss + (z * OS + y) * OS;
#pragma unroll
        for (int r2 = 0; r2 < 4; ++r2) {
          int xm = x0 + g * 4 + r2;
          if (xm < OS) op[xm] = acc[t][r2];
        }
      }
    }
  }
}

// ---------------- batch-norm reductions (two-stage, deterministic) ----------------
__global__ void stats1(const float* __restrict__ a, float* __restrict__ part,
                       int B, int C, int ss, int nblk) {
  int c = blockIdx.y;
  int tid = threadIdx.x;
  float s = 0.f, s2 = 0.f;
  for (int b = 0; b < B; ++b) {
    const float* ab = a + ((long)b * C + c) * ss;
    for (int p = blockIdx.x * blockDim.x + tid; p < ss; p += nblk * blockDim.x) {
      float x = ab[p];
      s += x;
      s2 += x * x;
    }
  }
  __shared__ float sh[256], sh2[256];
  sh[tid] = s; sh2[tid] = s2;
  __syncthreads();
  for (int off = 128; off > 0; off >>= 1) {
    if (tid < off) { sh[tid] += sh[tid + off]; sh2[tid] += sh2[tid + off]; }
    __syncthreads();
  }
  if (tid == 0) {
    part[(c * nblk + blockIdx.x) * 2 + 0] = sh[0];
    part[(c * nblk + blockIdx.x) * 2 + 1] = sh2[0];
  }
}

__global__ void stats2(const float* __restrict__ part, float* __restrict__ stats,
                       int nblk, float invn) {
  int c = blockIdx.x;
  int tid = threadIdx.x;
  float s = 0.f, s2 = 0.f;
  for (int i = tid; i < nblk; i += blockDim.x) {
    s += part[(c * nblk + i) * 2 + 0];
    s2 += part[(c * nblk + i) * 2 + 1];
  }
  __shared__ float sh[256], sh2[256];
  sh[tid] = s; sh2[tid] = s2;
  __syncthreads();
  for (int off = 128; off > 0; off >>= 1) {
    if (tid < off) { sh[tid] += sh[tid + off]; sh2[tid] += sh2[tid + off]; }
    __syncthreads();
  }
  if (tid == 0) {
    float m = sh[0] * invn;
    float var = sh2[0] * invn - m * m;
    stats[c * 2 + 0] = m;
    stats[c * 2 + 1] = 1.0f / sqrtf(var + EPSF);
  }
}

__global__ void bn_apply(const float* __restrict__ in, float* __restrict__ out,
                         const float* __restrict__ stats, const float* __restrict__ g,
                         const float* __restrict__ be, const float* __restrict__ bias,
                         int C, int ss, int relu) {
  int bc = blockIdx.y;
  int c = bc % C;
  float m = stats[c * 2 + 0];
  float r = stats[c * 2 + 1];
  float ga = g ? g[c] : 1.f;
  float bb = be ? be[c] : 0.f;
  float bi = bias ? bias[c] : 0.f;
  const float* ip = in + (long)bc * ss;
  float* op = out + (long)bc * ss;
  for (int p = blockIdx.x * blockDim.x + threadIdx.x; p < ss; p += gridDim.x * blockDim.x) {
    float xn = (ip[p] - m) * r * ga + bb;
    if (relu) xn = fmaxf(xn + bi, 0.f);
    op[p] = xn;
  }
}

// ---------------- pooling + final batch-norm ----------------
__global__ void pool_k(const float* __restrict__ in, float* __restrict__ pooled, int ss) {
  int bc = blockIdx.x;
  int tid = threadIdx.x;
  const float* p = in + (long)bc * ss;
  float s = 0.f;
  for (int e = tid; e < ss; e += blockDim.x) s += p[e];
  __shared__ float sh[256];
  sh[tid] = s;
  __syncthreads();
  for (int off = 128; off > 0; off >>= 1) {
    if (tid < off) sh[tid] += sh[tid + off];
    __syncthreads();
  }
  if (tid == 0) pooled[bc] = sh[0] / (float)ss;
}

__global__ void final_bn(const float* __restrict__ pooled, const float* __restrict__ g,
                         const float* __restrict__ be, float* __restrict__ out,
                         int B, int C) {
  int tid = threadIdx.x;
  __shared__ float mv[16][2];
  if (tid < C) {
    float s = 0.f, s2 = 0.f;
    for (int b = 0; b < B; ++b) {
      float x = pooled[b * C + tid];
      s += x;
      s2 += x * x;
    }
    float m = s / (float)B;
    float var = s2 / (float)B - m * m;
    mv[tid][0] = m;
    mv[tid][1] = 1.0f / sqrtf(var + EPSF);
  }
  __syncthreads();
  for (int i = tid; i < B * C; i += blockDim.x) {
    int c = i % C;
    out[i] = g[c] * (pooled[i] - mv[c][0]) * mv[c][1] + be[c];
  }
}

// ---------------- host ----------------
extern "C" void kernel_launch(void* const* d_in, const int* in_sizes, int n_in,
                              void* d_out, int out_size, void* d_ws, size_t ws_size,
                              hipStream_t stream) {
  (void)in_sizes; (void)n_in; (void)out_size; (void)ws_size;
  const float* x = (const float*)d_in[0];
  const float* w1[5]; const float* wA[5]; const float* wB[5];
  const float* bias[5]; const float* gam[5]; const float* bet[5];
  for (int i = 0; i < 5; ++i) {
    w1[i]  = (const float*)d_in[1 + i * 6 + 0];
    wA[i]  = (const float*)d_in[1 + i * 6 + 1];
    wB[i]  = (const float*)d_in[1 + i * 6 + 2];
    bias[i]= (const float*)d_in[1 + i * 6 + 3];
    gam[i] = (const float*)d_in[1 + i * 6 + 4];
    bet[i] = (const float*)d_in[1 + i * 6 + 5];
  }
  const float* gamma_out = (const float*)d_in[31];
  const float* beta_out  = (const float*)d_in[32];
  float* out = (float*)d_out;

  // workspace carve (~135 MB)
  float* A     = (float*)d_ws;            // 8,388,608
  float* Bb    = A + 8388608;             // 10,976,000
  float* V     = Bb + 10976000;           // 13,799,808 floats (f16 VT = 27.6M f16)
  float* K1    = V + 13799808;            // 128,000 floats (float4 K1)
  float* K2    = K1 + 128000;             // 384,000 floats (f16 K2L)
  float* part  = K2 + 384000;             // 8,192
  float* stats = part + 16 * 256 * 2;
  float* pooled= stats + 64;
  f16* VT  = (f16*)V;
  f16* K2h = (f16*)K2;

  const int NB = 256;
  const int Bn = 32;

  // --- input batch-norm (C=1, no affine) ---
  {
    int ss = 64 * 64 * 64;
    stats1<<<dim3(NB, 1), 256, 0, stream>>>(x, part, Bn, 1, ss, NB);
    stats2<<<1, 256, 0, stream>>>(part, stats, NB, 1.0f / (float)(Bn * (long)ss));
    int gx = (ss + 255) / 256;
    bn_apply<<<dim3(gx, Bn), 256, 0, stream>>>(x, A, stats, nullptr, nullptr, nullptr, 1, ss, 0);
  }

  const int SINs[5]  = {1, 8, 16, 16, 16};
  const int SOUTs[5] = {8, 16, 16, 16, 10};
  const int VECs[5]  = {4, 12, 16, 16, 13};
  const int ISs[5]   = {64, 35, 21, 14, 10};
  const int VSs[5]   = {33, 19, 12, 8, 6};
  const int OSs[5]   = {35, 21, 14, 10, 8};
  const int CP8s[5]  = {8, 24, 24, 24, 24};
  const int CHKs[5]  = {8, 16, 32, 32, 32};
  const int NPs[5]   = {2, 6, 8, 8, 7};
  const int ZTs[5]   = {8, 8, 8, 4, 4};

  float* sbuf = A;
  for (int i = 0; i < 5; ++i) {
    float* obuf = (i % 2 == 0) ? Bb : A;
    int IS = ISs[i], VS = VSs[i], OS = OSs[i];
    int VEC = VECs[i], SIN = SINs[i], SOUT = SOUTs[i];

    { int t = SIN * 125 * VEC;
      build_k1<<<(t + 255) / 256, 256, 0, stream>>>(w1[i], K1, VEC, SIN); }

    int CP8 = CP8s[i];
    int KS = CP8 / 4;
    int CHK = CHKs[i];
    int XG = (OS + 15) / 16;
    int ZTi = ZTs[i];
    int ZG = (OS + ZTi - 1) / ZTi;
    { int t = 125 * KS * 512;
      build_k2c<<<(t + 255) / 256, 256, 0, stream>>>(wA[i], wB[i], K2h, VEC, SOUT, KS); }
    for (int b0 = 0; b0 < Bn; b0 += CHK) {
      int bc = CHK;
      const float* sp = sbuf + (long)b0 * SIN * IS * IS * IS;
      float* op = obuf + (long)b0 * SOUT * OS * OS * OS;
      long waves = (long)bc * ZG * OS * XG;
      int g2 = (int)((waves * 64 + 255) / 256);
      if (i == 0) {
        int XG1 = (VS + 3) / 4;
        long t1 = (long)bc * VS * VS * XG1 * NPs[i];
        int g1 = (int)((t1 + 255) / 256);
        conv1_vt_x<1, 4, 8, 4><<<g1, 256, 0, stream>>>(sp, (const f32x4*)K1, VT, bc, IS, VS, XG1);
        conv2_mfma<8, 8, 8><<<g2, 256, 0, stream>>>(VT, K2h, op, bc, VS, OS, XG, ZG);
      } else if (i == 1) {
        int XG1 = (VS + 3) / 4;
        long t1 = (long)bc * VS * VS * XG1 * NPs[i];
        int g1 = (int)((t1 + 255) / 256);
        conv1_vt_x<8, 12, 24, 4><<<g1, 256, 0, stream>>>(sp, (const f32x4*)K1, VT, bc, IS, VS, XG1);
        conv2_mfma<24, 16, 8><<<g2, 256, 0, stream>>>(VT, K2h, op, bc, VS, OS, XG, ZG);
      } else if (i == 2) {
        int XG1 = (VS + 3) / 4;
        long t1 = (long)bc * VS * VS * XG1 * NPs[i];
        int g1 = (int)((t1 + 255) / 256);
        conv1_vt_x<16, 16, 24, 4><<<g1, 256, 0, stream>>>(sp, (const f32x4*)K1, VT, bc, IS, VS, XG1);
        conv2_mfma<24, 16, 8><<<g2, 256, 0, stream>>>(VT, K2h, op, bc, VS, OS, XG, ZG);
      } else {
        int XG1 = (VS + 3) / 4;
        int XP1 = XG1 * 4;
        float* Vp = obuf;
        long tA = (long)bc * VS * VS * NPs[i] * 4 * XG1;
        int gA = (int)((tA + 255) / 256);
        long tB = (long)bc * VS * VS * NPs[i] * VS;
        int gB = (int)((tB + 255) / 256);
        if (i == 3) {
          conv1_part<16, 4, 16><<<gA, 256, 0, stream>>>(sp, (const f32x4*)K1, Vp, bc, IS, VS, XG1, XP1);
          vt_pack<16, 4, 24><<<gB, 256, 0, stream>>>(Vp, VT, bc, VS, XP1);
          conv2_mfma<24, 16, 4><<<g2, 256, 0, stream>>>(VT, K2h, op, bc, VS, OS, XG, ZG);
        } else {
          conv1_part<16, 4, 13><<<gA, 256, 0, stream>>>(sp, (const f32x4*)K1, Vp, bc, IS, VS, XG1, XP1);
          vt_pack<13, 4, 24><<<gB, 256, 0, stream>>>(Vp, VT, bc, VS, XP1);
          conv2_mfma<24, 10, 4><<<g2, 256, 0, stream>>>(VT, K2h, op, bc, VS, OS, XG, ZG);
        }
      }
    }

    { int ss = OS * OS * OS;
      stats1<<<dim3(NB, SOUT), 256, 0, stream>>>(obuf, part, Bn, SOUT, ss, NB);
      stats2<<<SOUT, 256, 0, stream>>>(part, stats, NB, 1.0f / (float)((long)Bn * ss));
      int gx = (ss + 255) / 256;
      bn_apply<<<dim3(gx, Bn * SOUT), 256, 0, stream>>>(obuf, obuf, stats, gam[i], bet[i],
                                                        bias[i], SOUT, ss, (i < 4) ? 1 : 0);
    }
    sbuf = obuf;
  }

  pool_k<<<Bn * 10, 256, 0, stream>>>(sbuf, pooled, 8 * 8 * 8);
  final_bn<<<1, 64, 0, stream>>>(pooled, gamma_out, beta_out, out, Bn, 10);
}